// Round 5
// baseline (226.305 us; speedup 1.0000x reference)
//
#include <hip/hip_runtime.h>

#define HH 640
#define WW 640
#define CIN 3
#define COUT 64
#define KK 7
#define NS 100000
#define OHh 319
#define OWw 319
#define PW 646                 // padded width/height
#define PROWF (PW * CIN)       // 1938 floats per padded row
#define WROW 1344              // LDS floats per kernel row: 5*256 + 64
#define OWNER_BLKS 391         // ceil(NS/256)
#define PAD_BLKS 1631          // ceil(646*646/256)

// bf16 helpers (RNE)
__device__ __forceinline__ unsigned short f2bf(float x) {
    unsigned u = __float_as_uint(x);
    unsigned r = (u + 0x7FFFu + ((u >> 16) & 1u)) >> 16;
    return (unsigned short)r;
}
__device__ __forceinline__ float bf2f(unsigned short b) {
    return __uint_as_float((unsigned)b << 16);
}

// Per-wave int64/int32 layout detection: OR of the first 64 odd dwords.
// int64 (LE, values<640) -> all high words zero. int32 -> col values,
// P(all 64 == 0) = (1/640)^64 ~ 0. Same samples every wave -> consistent.
__device__ __forceinline__ bool detect_is64(const int* __restrict__ loc) {
    const int smp = loc[1 + 2 * (int)(threadIdx.x & 63)];
    return __ballot(smp != 0) == 0ULL;
}

// ---- fused: owner scatter (last-write-wins via atomicMax) + zero-pad copy ----
__global__ __launch_bounds__(256) void prep_kernel(
        const int* __restrict__ loc, const float* __restrict__ fm,
        int* __restrict__ owner, float* __restrict__ pfm) {
    const bool is64 = detect_is64(loc);
    if (blockIdx.x < OWNER_BLKS) {
        const int n = blockIdx.x * 256 + threadIdx.x;
        if (n < NS) {
            int r, c;
            if (is64) { r = loc[4 * n]; c = loc[4 * n + 2]; }
            else      { r = loc[2 * n]; c = loc[2 * n + 1]; }
            atomicMax(&owner[r * WW + c], n);
        }
    } else {
        const int pix = (blockIdx.x - OWNER_BLKS) * 256 + threadIdx.x;
        if (pix < PW * PW) {
            const int r = pix / PW, c = pix % PW;
            float v0 = 0.0f, v1 = 0.0f, v2 = 0.0f;
            if (r >= 3 && r < 643 && c >= 3 && c < 643) {
                const float* s = fm + ((size_t)(r - 3) * WW + (c - 3)) * CIN;
                v0 = s[0]; v1 = s[1]; v2 = s[2];
            }
            float* d = pfm + (size_t)pix * CIN;
            d[0] = v0; d[1] = v1; d[2] = v2;
        }
    }
}

// ---- per-site conv + BN + ReLU -> feats[NS][64] (bf16) ----
// 4 sites/wave, lane = cout. Patch loads are per-lane VMEM broadcasts
// (addresses laundered into VGPRs): in-order returns -> fine-grained vmcnt
// overlap, unlike scalar loads (out-of-order -> lgkmcnt(0) full drain).
__global__ __launch_bounds__(256) void feats_kernel(
        const int* __restrict__ loc, const float* __restrict__ pfm,
        const float* __restrict__ wgt, const float* __restrict__ gamma,
        const float* __restrict__ beta, const float* __restrict__ mean,
        const float* __restrict__ var, const int* __restrict__ owner,
        unsigned short* __restrict__ feats) {
    __shared__ float WL[KK * WROW];  // 9408 floats = 37632 B -> 4 blocks/CU
    for (int u = threadIdx.x; u < KK * 21 * COUT; u += 256) {
        const int cout = u & 63;
        const int k = (u >> 6) % 21;
        const int i = u / (21 * 64);
        const int off = (k < 20) ? (i * WROW + (k >> 2) * 256 + cout * 4 + (k & 3))
                                 : (i * WROW + 1280 + cout);
        WL[off] = wgt[u];  // u == (i*21+k)*64+cout
    }
    const bool is64 = detect_is64(loc);
    __syncthreads();

    const int lane = threadIdx.x & 63;
    const int wv = threadIdx.x >> 6;
    const float inv = gamma[lane] * rsqrtf(var[lane] + 1e-5f);
    const float bias = beta[lane] - mean[lane] * inv;

    for (int bg = blockIdx.x; bg < NS / 16; bg += gridDim.x) {
        const int n0 = bg * 16 + wv * 4;

        const float* ptr[4];
        bool alive[4];
        #pragma unroll
        for (int s = 0; s < 4; ++s) {
            const int n = n0 + s;
            int r, c;
            if (is64) { r = loc[4 * n]; c = loc[4 * n + 2]; }
            else      { r = loc[2 * n]; c = loc[2 * n + 1]; }
            alive[s] = (owner[r * WW + c] == n);
            int off = (r * PW + c) * CIN;
            asm("" : "+v"(off));   // force VGPR address -> VMEM broadcast load
            ptr[s] = pfm + off;
        }

        float acc[4] = {0.0f, 0.0f, 0.0f, 0.0f};
        #pragma unroll 1
        for (int i = 0; i < KK; ++i) {
            // chunk A: k = 0..11 (3 float4 weight groups)
            {
                float a[4][12];
                #pragma unroll
                for (int s = 0; s < 4; ++s)
                    __builtin_memcpy(&a[s][0], ptr[s] + i * PROWF, 48);
                #pragma unroll
                for (int g = 0; g < 3; ++g) {
                    const float4 w = *(const float4*)&WL[i * WROW + g * 256 + lane * 4];
                    #pragma unroll
                    for (int s = 0; s < 4; ++s) {
                        acc[s] = fmaf(a[s][g * 4 + 0], w.x, acc[s]);
                        acc[s] = fmaf(a[s][g * 4 + 1], w.y, acc[s]);
                        acc[s] = fmaf(a[s][g * 4 + 2], w.z, acc[s]);
                        acc[s] = fmaf(a[s][g * 4 + 3], w.w, acc[s]);
                    }
                }
            }
            // chunk B: k = 12..20 (2 float4 groups + scalar k=20)
            {
                float b[4][9];
                #pragma unroll
                for (int s = 0; s < 4; ++s)
                    __builtin_memcpy(&b[s][0], ptr[s] + i * PROWF + 12, 36);
                #pragma unroll
                for (int g = 0; g < 2; ++g) {
                    const float4 w = *(const float4*)&WL[i * WROW + (3 + g) * 256 + lane * 4];
                    #pragma unroll
                    for (int s = 0; s < 4; ++s) {
                        acc[s] = fmaf(b[s][g * 4 + 0], w.x, acc[s]);
                        acc[s] = fmaf(b[s][g * 4 + 1], w.y, acc[s]);
                        acc[s] = fmaf(b[s][g * 4 + 2], w.z, acc[s]);
                        acc[s] = fmaf(b[s][g * 4 + 3], w.w, acc[s]);
                    }
                }
                const float w20 = WL[i * WROW + 1280 + lane];
                #pragma unroll
                for (int s = 0; s < 4; ++s) acc[s] = fmaf(b[s][8], w20, acc[s]);
            }
        }
        #pragma unroll
        for (int s = 0; s < 4; ++s)
            if (alive[s])
                feats[(size_t)(n0 + s) * COUT + lane] =
                    f2bf(fmaxf(acc[s] * inv + bias, 0.0f));
    }
}

// ---- 3x3 stride-2 max pool from owner map + bf16 feats; 4 px per wave ----
__global__ __launch_bounds__(256) void pool_kernel(
        const int* __restrict__ owner, const unsigned short* __restrict__ feats,
        float* __restrict__ out) {
    const int lane = threadIdx.x & 63;
    const int TPR = 80;  // ceil(319/4)
    const int task = __builtin_amdgcn_readfirstlane(blockIdx.x * 4 + (threadIdx.x >> 6));
    if (task >= OHh * TPR) return;
    const int oh = task / TPR, ow0 = (task % TPR) * 4;
    const int r0 = oh * 2, c0 = ow0 * 2;

    int ov[3][9];
    #pragma unroll
    for (int dy = 0; dy < 3; ++dy) {
        const int* orow = owner + (r0 + dy) * WW + c0;
        #pragma unroll
        for (int dx = 0; dx < 9; ++dx)
            ov[dy][dx] = (c0 + dx < WW) ? orow[dx] : -1;
    }
    #pragma unroll
    for (int q = 0; q < 4; ++q) {
        const int ow = ow0 + q;
        if (ow >= OWw) break;
        float m = 0.0f;
        #pragma unroll
        for (int dy = 0; dy < 3; ++dy)
            #pragma unroll
            for (int dx = 0; dx < 3; ++dx) {
                const int o = ov[dy][2 * q + dx];
                if (o >= 0) m = fmaxf(m, bf2f(feats[(size_t)o * COUT + lane]));
            }
        out[(size_t)(oh * OWw + ow) * COUT + lane] = m;
    }
}

extern "C" void kernel_launch(void* const* d_in, const int* in_sizes, int n_in,
                              void* d_out, int out_size, void* d_ws, size_t ws_size,
                              hipStream_t stream) {
    const int*   loc   = (const int*)d_in[0];
    const float* fm    = (const float*)d_in[1];
    const float* wgt   = (const float*)d_in[2];
    const float* gamma = (const float*)d_in[3];
    const float* beta  = (const float*)d_in[4];
    const float* mean  = (const float*)d_in[5];
    const float* var   = (const float*)d_in[6];
    float* out = (float*)d_out;

    char* ws = (char*)d_ws;
    int* owner = (int*)ws;                                        // 1638400 B
    unsigned short* feats = (unsigned short*)(ws + 1638400);      // 12.8 MB
    float* pfm = (float*)(ws + 1638400 + (size_t)NS * COUT * 2);  // 5.0 MB
    // total ~19.4 MB

    hipMemsetAsync(owner, 0xFF, (size_t)HH * WW * sizeof(int), stream);  // owner = -1
    prep_kernel<<<OWNER_BLKS + PAD_BLKS, 256, 0, stream>>>(loc, fm, owner, pfm);
    feats_kernel<<<1024, 256, 0, stream>>>(loc, pfm, wgt, gamma, beta, mean, var,
                                           owner, feats);
    pool_kernel<<<(OHh * 80) / 4, 256, 0, stream>>>(owner, feats, out);
}

// Round 6
// 142.439 us; speedup vs baseline: 1.5888x; 1.5888x over previous
//
#include <hip/hip_runtime.h>

#define HH 640
#define WW 640
#define CIN 3
#define COUT 64
#define KK 7
#define NS 100000
#define OHh 319
#define OWw 319
#define PW 646                  // padded width/height (pixels)
#define OWNER_BLKS 391          // ceil(NS/256)
#define PAD_BLKS 1631           // ceil(646*646/256)

typedef _Float16 half2_t __attribute__((ext_vector_type(2)));

#if defined(__has_builtin)
#if __has_builtin(__builtin_amdgcn_fdot2)
#define HAVE_FDOT2 1
#endif
#endif

union H2U { unsigned u; half2_t h; };
__device__ __forceinline__ half2_t h2(unsigned x) { H2U t; t.u = x; return t.h; }
__device__ __forceinline__ float FDOT2(unsigned a, unsigned b, float c) {
#ifdef HAVE_FDOT2
    return __builtin_amdgcn_fdot2(h2(a), h2(b), c, false);
#else
    half2_t ha = h2(a), hb = h2(b);
    return fmaf((float)ha.x, (float)hb.x, fmaf((float)ha.y, (float)hb.y, c));
#endif
}

// bf16 helpers (RNE)
__device__ __forceinline__ unsigned short f2bf(float x) {
    unsigned u = __float_as_uint(x);
    return (unsigned short)((u + 0x7FFFu + ((u >> 16) & 1u)) >> 16);
}
__device__ __forceinline__ float bf2f(unsigned short b) {
    return __uint_as_float((unsigned)b << 16);
}

// Per-wave int64/int32 layout detection: OR of the first 64 odd dwords.
__device__ __forceinline__ bool detect_is64(const int* __restrict__ loc) {
    const int smp = loc[1 + 2 * (int)(threadIdx.x & 63)];
    return __ballot(smp != 0) == 0ULL;
}

// ---- fused: owner scatter (last-write-wins) + fp16 pad/pack of fm ----
// pfm_h: per pixel a uint2 = {pack(c0,c1), pack(c2,0)} -> 8 B, dword-aligned.
__global__ __launch_bounds__(256) void prep_kernel(
        const int* __restrict__ loc, const float* __restrict__ fm,
        int* __restrict__ owner, uint2* __restrict__ pfm) {
    const bool is64 = detect_is64(loc);
    if (blockIdx.x < OWNER_BLKS) {
        const int n = blockIdx.x * 256 + threadIdx.x;
        if (n < NS) {
            int r, c;
            if (is64) { r = loc[4 * n]; c = loc[4 * n + 2]; }
            else      { r = loc[2 * n]; c = loc[2 * n + 1]; }
            atomicMax(&owner[r * WW + c], n);
        }
    } else {
        const int pix = (blockIdx.x - OWNER_BLKS) * 256 + threadIdx.x;
        if (pix < PW * PW) {
            const int r = pix / PW, c = pix % PW;
            _Float16 v0 = 0, v1 = 0, v2 = 0;
            if (r >= 3 && r < 643 && c >= 3 && c < 643) {
                const float* s = fm + ((size_t)(r - 3) * WW + (c - 3)) * CIN;
                v0 = (_Float16)s[0]; v1 = (_Float16)s[1]; v2 = (_Float16)s[2];
            }
            H2U a, b;
            a.h = half2_t{v0, v1};
            b.h = half2_t{v2, (_Float16)0};
            pfm[pix] = make_uint2(a.u, b.u);
        }
    }
}

// ---- per-site conv + BN + ReLU -> feats[NS][64] (bf16) ----
// 4 sites/wave, lane = cout. Patch: wave-uniform scalar loads of 56 B/row
// (7 pixels x 2 dwords of packed f16). Weights: LDS packed half2 per
// (row, pixel, cout) -> ds_read_b64 shared by 4 sites; v_dot2_f32_f16 MACs.
// LDS = 25088 B -> 6 blocks/CU = 6 waves/SIMD.
__global__ __launch_bounds__(256, 6) void feats_kernel(
        const int* __restrict__ loc, const unsigned* __restrict__ pfm,
        const float* __restrict__ wgt, const float* __restrict__ gamma,
        const float* __restrict__ beta, const float* __restrict__ mean,
        const float* __restrict__ var, const int* __restrict__ owner,
        unsigned short* __restrict__ feats) {
    __shared__ unsigned WLu[KK * KK * COUT * 2];  // [(i*7+j)*64+cout]*2 -> 25088 B
    for (int u = threadIdx.x; u < KK * KK * COUT; u += 256) {
        const int cout = u & 63;
        const int ij = u >> 6;            // i*7+j
        const int i = ij / 7, j = ij - 7 * i;
        const float w0 = wgt[((i * 7 + j) * 3 + 0) * COUT + cout];
        const float w1 = wgt[((i * 7 + j) * 3 + 1) * COUT + cout];
        const float w2 = wgt[((i * 7 + j) * 3 + 2) * COUT + cout];
        H2U a, b;
        a.h = half2_t{(_Float16)w0, (_Float16)w1};
        b.h = half2_t{(_Float16)w2, (_Float16)0};
        *(uint2*)&WLu[(size_t)u * 2] = make_uint2(a.u, b.u);
    }
    const bool is64 = detect_is64(loc);
    __syncthreads();

    const int lane = threadIdx.x & 63;
    const int wv = threadIdx.x >> 6;
    const float inv = gamma[lane] * rsqrtf(var[lane] + 1e-5f);
    const float bias = beta[lane] - mean[lane] * inv;

    for (int bg = blockIdx.x; bg < NS / 16; bg += gridDim.x) {
        const int n0 = __builtin_amdgcn_readfirstlane(bg * 16 + wv * 4);

        const unsigned* pu[4];
        bool alive[4];
        #pragma unroll
        for (int s = 0; s < 4; ++s) {
            const int n = n0 + s;
            int r, c;
            if (is64) { r = loc[4 * n]; c = loc[4 * n + 2]; }
            else      { r = loc[2 * n]; c = loc[2 * n + 1]; }
            r = __builtin_amdgcn_readfirstlane(r);
            c = __builtin_amdgcn_readfirstlane(c);
            alive[s] = (owner[r * WW + c] == n);
            pu[s] = pfm + (size_t)(r * PW + c) * 2;   // uniform -> scalar loads
        }

        float acc[4] = {0.0f, 0.0f, 0.0f, 0.0f};
        #pragma unroll 1
        for (int i = 0; i < KK; ++i) {
            unsigned d[4][14];
            #pragma unroll
            for (int s = 0; s < 4; ++s)
                __builtin_memcpy(&d[s][0], pu[s] + (size_t)i * (PW * 2), 56);
            uint2 wp[KK];
            #pragma unroll
            for (int j = 0; j < KK; ++j)
                wp[j] = *(const uint2*)&WLu[(size_t)(((i * 7 + j) << 6) + lane) * 2];
            #pragma unroll
            for (int j = 0; j < KK; ++j) {
                #pragma unroll
                for (int s = 0; s < 4; ++s) {
                    acc[s] = FDOT2(d[s][2 * j + 0], wp[j].x, acc[s]);
                    acc[s] = FDOT2(d[s][2 * j + 1], wp[j].y, acc[s]);
                }
            }
        }
        #pragma unroll
        for (int s = 0; s < 4; ++s)
            if (alive[s])
                feats[(size_t)(n0 + s) * COUT + lane] =
                    f2bf(fmaxf(acc[s] * inv + bias, 0.0f));
    }
}

// ---- 3x3 stride-2 max pool; 4 px/wave, 27 unconditional clamped gathers ----
__global__ __launch_bounds__(256) void pool_kernel(
        const int* __restrict__ owner, const unsigned short* __restrict__ feats,
        float* __restrict__ out) {
    const int lane = threadIdx.x & 63;
    const int TPR = 80;  // ceil(319/4)
    const int task = __builtin_amdgcn_readfirstlane(blockIdx.x * 4 + (threadIdx.x >> 6));
    if (task >= OHh * TPR) return;
    const int oh = task / TPR, ow0 = (task % TPR) * 4;
    const int r0 = oh * 2, c0 = ow0 * 2;

    int ov[3][9];
    #pragma unroll
    for (int dy = 0; dy < 3; ++dy)
        __builtin_memcpy(&ov[dy][0], owner + (r0 + dy) * WW + c0, 36);  // uniform

    // all 27 gathers issue unconditionally (clamped index), masked by cndmask
    float v[3][9];
    #pragma unroll
    for (int dy = 0; dy < 3; ++dy)
        #pragma unroll
        for (int dx = 0; dx < 9; ++dx) {
            const int o = ov[dy][dx];
            const int oc = o < 0 ? 0 : o;
            const float f = bf2f(feats[(size_t)oc * COUT + lane]);
            v[dy][dx] = (o >= 0) ? f : 0.0f;
        }

    #pragma unroll
    for (int q = 0; q < 4; ++q) {
        const int ow = ow0 + q;
        if (ow >= OWw) break;
        float m = 0.0f;
        #pragma unroll
        for (int dy = 0; dy < 3; ++dy)
            #pragma unroll
            for (int dx = 0; dx < 3; ++dx)
                m = fmaxf(m, v[dy][2 * q + dx]);
        out[(size_t)(oh * OWw + ow) * COUT + lane] = m;
    }
}

extern "C" void kernel_launch(void* const* d_in, const int* in_sizes, int n_in,
                              void* d_out, int out_size, void* d_ws, size_t ws_size,
                              hipStream_t stream) {
    const int*   loc   = (const int*)d_in[0];
    const float* fm    = (const float*)d_in[1];
    const float* wgt   = (const float*)d_in[2];
    const float* gamma = (const float*)d_in[3];
    const float* beta  = (const float*)d_in[4];
    const float* mean  = (const float*)d_in[5];
    const float* var   = (const float*)d_in[6];
    float* out = (float*)d_out;

    char* ws = (char*)d_ws;
    int* owner = (int*)ws;                                        // 1638400 B
    unsigned short* feats = (unsigned short*)(ws + 1638400);      // 12.8 MB
    uint2* pfm = (uint2*)(ws + 1638400 + (size_t)NS * COUT * 2);  // 646*646*8 = 3.34 MB
    // total ~17.8 MB

    hipMemsetAsync(owner, 0xFF, (size_t)HH * WW * sizeof(int), stream);  // owner = -1
    prep_kernel<<<OWNER_BLKS + PAD_BLKS, 256, 0, stream>>>(loc, fm, owner, pfm);
    feats_kernel<<<1536, 256, 0, stream>>>(loc, (const unsigned*)pfm, wgt, gamma,
                                           beta, mean, var, owner, feats);
    pool_kernel<<<(OHh * 80) / 4, 256, 0, stream>>>(owner, feats, out);
}

// Round 7
// 125.267 us; speedup vs baseline: 1.8066x; 1.1371x over previous
//
#include <hip/hip_runtime.h>

#define HH 640
#define WW 640
#define COUT 64
#define KK 7
#define NS 100000
#define OHh 319
#define OWw 319
#define PWY 646                 // pfm rows
#define PWX 648                 // pfm row stride in pixels (8 B each)
#define OWNER_BLKS 391          // ceil(NS/256)
#define PAD_BLKS ((PWY * PWX + 255) / 256)
#define NBLK 1563               // ceil(NS/64): 64 sites per block (4 waves x 16)

typedef _Float16 half2_t __attribute__((ext_vector_type(2)));
typedef _Float16 h8 __attribute__((ext_vector_type(8)));
typedef float f4 __attribute__((ext_vector_type(4)));
typedef uint4 u4a __attribute__((aligned(8)));   // 16B load at 8B alignment

union H2U { unsigned u; half2_t h; };
union H8U { uint4 u; h8 h; _Float16 e[8]; };

// bf16 helpers (RNE)
__device__ __forceinline__ unsigned short f2bf(float x) {
    unsigned u = __float_as_uint(x);
    return (unsigned short)((u + 0x7FFFu + ((u >> 16) & 1u)) >> 16);
}
__device__ __forceinline__ float bf2f(unsigned short b) {
    return __uint_as_float((unsigned)b << 16);
}

// Per-wave int64/int32 layout detection: OR of the first 64 odd dwords.
__device__ __forceinline__ bool detect_is64(const int* __restrict__ loc) {
    const int smp = loc[1 + 2 * (int)(threadIdx.x & 63)];
    return __ballot(smp != 0) == 0ULL;
}

// ---- fused: owner scatter (last-write-wins) + fp16 pad/pack of fm ----
// pfm: per pixel uint2 = {pack(c0,c1), pack(c2,0)}; rows 0..645, cols 0..647
// (cols 643..647 zero; pfm[r][c] == fm[r-3][c-3]).
__global__ __launch_bounds__(256) void prep_kernel(
        const int* __restrict__ loc, const float* __restrict__ fm,
        int* __restrict__ owner, uint2* __restrict__ pfm) {
    const bool is64 = detect_is64(loc);
    if (blockIdx.x < OWNER_BLKS) {
        const int n = blockIdx.x * 256 + threadIdx.x;
        if (n < NS) {
            int r, c;
            if (is64) { r = loc[4 * n]; c = loc[4 * n + 2]; }
            else      { r = loc[2 * n]; c = loc[2 * n + 1]; }
            atomicMax(&owner[r * WW + c], n);
        }
    } else {
        const int pix = (blockIdx.x - OWNER_BLKS) * 256 + threadIdx.x;
        if (pix < PWY * PWX) {
            const int r = pix / PWX, c = pix - r * PWX;
            _Float16 v0 = 0, v1 = 0, v2 = 0;
            if (r >= 3 && r < 643 && c >= 3 && c < 643) {
                const float* s = fm + ((size_t)(r - 3) * WW + (c - 3)) * 3;
                v0 = (_Float16)s[0]; v1 = (_Float16)s[1]; v2 = (_Float16)s[2];
            }
            H2U a, b;
            a.h = half2_t{v0, v1};
            b.h = half2_t{v2, (_Float16)0};
            pfm[pix] = make_uint2(a.u, b.u);
        }
    }
}

// ---- MFMA feats: 16 sites/wave, D[site][cout] = patch . W, +BN+ReLU ----
// K = 224 (7 rows x 8 px x 4 ch; px7 & ch3 have zero weights).
// A-frag: lane(m=lane&15, q=lane>>4) holds patch[m][k=q*8..q*8+7] = 2 pixels,
//         one 16B global load per row step.  B-frag: LDS ds_read_b128.
// C/D: cout = t*16 + (lane&15), site = q*4 + reg   (m89/m91 mapping).
__global__ __launch_bounds__(256) void feats_kernel(
        const int* __restrict__ loc, const uint2* __restrict__ pfm,
        const float* __restrict__ wgt, const float* __restrict__ gamma,
        const float* __restrict__ beta, const float* __restrict__ mean,
        const float* __restrict__ var, const int* __restrict__ owner,
        unsigned short* __restrict__ feats) {
    __shared__ uint4 WB[4 * KK * 64];   // [t][i][lane] -> 8 f16; 28672 B
    for (int e = threadIdx.x; e < 4 * KK * 64; e += 256) {
        const int t = e / (KK * 64);
        const int rem = e - t * KK * 64;
        const int i = rem >> 6, l = rem & 63;
        const int cout = t * 16 + (l & 15);
        const int q = l >> 4;
        H8U w;
        #pragma unroll
        for (int j = 0; j < 8; ++j) {
            const int kl = q * 8 + j, px = kl >> 2, ci = kl & 3;
            const float v = (px < KK && ci < 3)
                              ? wgt[((i * KK + px) * 3 + ci) * COUT + cout] : 0.0f;
            w.e[j] = (_Float16)v;
        }
        WB[e] = w.u;
    }
    const bool is64 = detect_is64(loc);
    __syncthreads();

    const int lane = threadIdx.x & 63;
    const int q = lane >> 4;
    const int n0 = (blockIdx.x * 4 + (threadIdx.x >> 6)) * 16;

    // A-side site (m = lane&15)
    {
    }
    const int nA = min(n0 + (lane & 15), NS - 1);
    int rA, cA;
    if (is64) { rA = loc[4 * nA]; cA = loc[4 * nA + 2]; }
    else      { rA = loc[2 * nA]; cA = loc[2 * nA + 1]; }
    int aidx = rA * PWX + cA + 2 * q;   // uint2 index; +PWX per row step

    // store-side sites (m = q*4 + p) -> alive mask
    bool alive[4];
    #pragma unroll
    for (int p = 0; p < 4; ++p) {
        const int nS = n0 + q * 4 + p;
        const int nSc = min(nS, NS - 1);
        int r, c;
        if (is64) { r = loc[4 * nSc]; c = loc[4 * nSc + 2]; }
        else      { r = loc[2 * nSc]; c = loc[2 * nSc + 1]; }
        alive[p] = (nS < NS) && (owner[r * WW + c] == nS);
    }

    // BN params for cout = t*16 + (lane&15)
    float invt[4], bist[4];
    #pragma unroll
    for (int t = 0; t < 4; ++t) {
        const int co = t * 16 + (lane & 15);
        const float iv = gamma[co] * rsqrtf(var[co] + 1e-5f);
        invt[t] = iv; bist[t] = beta[co] - mean[co] * iv;
    }

    f4 acc[4] = {f4{0,0,0,0}, f4{0,0,0,0}, f4{0,0,0,0}, f4{0,0,0,0}};
    #pragma unroll
    for (int i = 0; i < KK; ++i) {
        H8U a;
        a.u = *(const u4a*)(pfm + aidx + i * PWX);   // 16B gather, vmcnt
        #pragma unroll
        for (int t = 0; t < 4; ++t) {
            H8U b;
            b.u = WB[(t * KK + i) * 64 + lane];       // ds_read_b128
            acc[t] = __builtin_amdgcn_mfma_f32_16x16x32_f16(a.h, b.h, acc[t], 0, 0, 0);
        }
    }

    unsigned short* dump = feats + (size_t)NS * COUT;  // scratch slot
    #pragma unroll
    for (int t = 0; t < 4; ++t) {
        #pragma unroll
        for (int p = 0; p < 4; ++p) {
            const float v = fmaxf(acc[t][p] * invt[t] + bist[t], 0.0f);
            const int nS = n0 + q * 4 + p;
            unsigned short* addr = alive[p]
                ? feats + (size_t)nS * COUT + t * 16 + (lane & 15)
                : dump + lane;
            *addr = f2bf(v);
        }
    }
}

// ---- 3x3 stride-2 max pool; 4 px/wave; scalar-branch skip of empty cells ----
__global__ __launch_bounds__(256) void pool_kernel(
        const int* __restrict__ owner, const unsigned short* __restrict__ feats,
        float* __restrict__ out) {
    const int lane = threadIdx.x & 63;
    const int TPR = 80;  // ceil(319/4)
    const int task = __builtin_amdgcn_readfirstlane(blockIdx.x * 4 + (threadIdx.x >> 6));
    if (task >= OHh * TPR) return;
    const int oh = task / TPR, ow0 = (task % TPR) * 4;
    const int r0 = oh * 2, c0 = ow0 * 2;

    int ov[3][9];
    #pragma unroll
    for (int dy = 0; dy < 3; ++dy)
        __builtin_memcpy(&ov[dy][0], owner + (r0 + dy) * WW + c0, 36);  // s_loads

    // ~78% of cells are empty: wave-uniform branch skips the gather entirely;
    // taken loads are independent -> batched, one vmcnt drain at the maxes.
    float v[3][9];
    #pragma unroll
    for (int dy = 0; dy < 3; ++dy)
        #pragma unroll
        for (int dx = 0; dx < 9; ++dx) {
            const int o = __builtin_amdgcn_readfirstlane(ov[dy][dx]);
            float f = 0.0f;
            if (o >= 0) f = bf2f(feats[(size_t)o * COUT + lane]);
            v[dy][dx] = f;
        }

    #pragma unroll
    for (int qq = 0; qq < 4; ++qq) {
        const int ow = ow0 + qq;
        if (ow >= OWw) break;
        float m = 0.0f;
        #pragma unroll
        for (int dy = 0; dy < 3; ++dy)
            #pragma unroll
            for (int dx = 0; dx < 3; ++dx)
                m = fmaxf(m, v[dy][2 * qq + dx]);
        out[(size_t)(oh * OWw + ow) * COUT + lane] = m;
    }
}

extern "C" void kernel_launch(void* const* d_in, const int* in_sizes, int n_in,
                              void* d_out, int out_size, void* d_ws, size_t ws_size,
                              hipStream_t stream) {
    const int*   loc   = (const int*)d_in[0];
    const float* fm    = (const float*)d_in[1];
    const float* wgt   = (const float*)d_in[2];
    const float* gamma = (const float*)d_in[3];
    const float* beta  = (const float*)d_in[4];
    const float* mean  = (const float*)d_in[5];
    const float* var   = (const float*)d_in[6];
    float* out = (float*)d_out;

    char* ws = (char*)d_ws;
    int* owner = (int*)ws;                                        // 1638400 B
    unsigned short* feats = (unsigned short*)(ws + 1638400);      // 12.8 MB + dump
    uint2* pfm = (uint2*)(ws + 1638400 + (size_t)NS * COUT * 2 + 256);
    // pfm: 646*648*8 = 3.35 MB; total ~17.8 MB

    hipMemsetAsync(owner, 0xFF, (size_t)HH * WW * sizeof(int), stream);  // owner=-1
    prep_kernel<<<OWNER_BLKS + PAD_BLKS, 256, 0, stream>>>(loc, fm, owner, pfm);
    feats_kernel<<<NBLK, 256, 0, stream>>>(loc, pfm, wgt, gamma, beta, mean, var,
                                           owner, feats);
    pool_kernel<<<(OHh * 80) / 4, 256, 0, stream>>>(owner, feats, out);
}

// Round 8
// 121.606 us; speedup vs baseline: 1.8610x; 1.0301x over previous
//
#include <hip/hip_runtime.h>

#define HH 640
#define WW 640
#define COUT 64
#define KK 7
#define NS 100000
#define OHh 319
#define OWw 319
#define PWY 646                 // pfm rows
#define PWX 648                 // pfm row stride in pixels (8 B each)
#define OWNER_BLKS 391          // ceil(NS/256)
#define PAD_BLKS ((PWY * PWX / 2 + 255) / 256)   // 2 px per thread
#define NBLK 1563               // ceil(NS/64): 64 sites per block (4 waves x 16)

typedef _Float16 half2_t __attribute__((ext_vector_type(2)));
typedef _Float16 h8 __attribute__((ext_vector_type(8)));
typedef float f4 __attribute__((ext_vector_type(4)));
typedef uint4 u4a __attribute__((aligned(8)));   // 16B load at 8B alignment

union H2U { unsigned u; half2_t h; };
union H8U { uint4 u; h8 h; _Float16 e[8]; };

// bf16 helpers (RNE)
__device__ __forceinline__ unsigned short f2bf(float x) {
    unsigned u = __float_as_uint(x);
    return (unsigned short)((u + 0x7FFFu + ((u >> 16) & 1u)) >> 16);
}
__device__ __forceinline__ float bf2f(unsigned short b) {
    return __uint_as_float((unsigned)b << 16);
}

// Per-wave int64/int32 layout detection: OR of the first 64 odd dwords.
__device__ __forceinline__ bool detect_is64(const int* __restrict__ loc) {
    const int smp = loc[1 + 2 * (int)(threadIdx.x & 63)];
    return __ballot(smp != 0) == 0ULL;
}

// ---- fused: owner scatter (last-write-wins) + fp16 pad/pack of fm ----
// pfm: per pixel uint2 = {pack(c0,c1), pack(c2,0)}; pfm[r][c] == fm[r-3][c-3].
__global__ __launch_bounds__(256) void prep_kernel(
        const int* __restrict__ loc, const float* __restrict__ fm,
        int* __restrict__ owner, uint2* __restrict__ pfm) {
    const bool is64 = detect_is64(loc);
    if (blockIdx.x < OWNER_BLKS) {
        const int n = blockIdx.x * 256 + threadIdx.x;
        if (n < NS) {
            int r, c;
            if (is64) { r = loc[4 * n]; c = loc[4 * n + 2]; }
            else      { r = loc[2 * n]; c = loc[2 * n + 1]; }
            atomicMax(&owner[r * WW + c], n);
        }
    } else {
        const int pair = (blockIdx.x - OWNER_BLKS) * 256 + threadIdx.x;
        const int pix = pair * 2;
        if (pix < PWY * PWX) {
            const int r = pix / PWX, c = pix - r * PWX;
            uint4 o;
            H2U a0, b0, a1, b1;
            a0.u = b0.u = a1.u = b1.u = 0;
            if (r >= 3 && r < 643) {
                const float* s = fm + ((size_t)(r - 3) * WW + (c - 3)) * 3;
                if (c >= 3 && c < 643) {
                    a0.h = half2_t{(_Float16)s[0], (_Float16)s[1]};
                    b0.h = half2_t{(_Float16)s[2], (_Float16)0};
                }
                if (c + 1 >= 3 && c + 1 < 643) {
                    a1.h = half2_t{(_Float16)s[3], (_Float16)s[4]};
                    b1.h = half2_t{(_Float16)s[5], (_Float16)0};
                }
            }
            o.x = a0.u; o.y = b0.u; o.z = a1.u; o.w = b1.u;
            *(uint4*)(pfm + pix) = o;   // 16B aligned (pix even)
        }
    }
}

// ---- MFMA feats: 16 sites/wave, D[site][cout] = patch . W, +BN+ReLU ----
// K = 224 (7 rows x 8 px x 4 ch; px7 & ch3 zero-weighted).
// A-frag: lane(m=lane&15, q=lane>>4) holds patch[m][k=q*8..q*8+7] = 2 pixels,
//         one 16B global load per row step.  B-frag: LDS ds_read_b128.
// C/D: cout = t*16 + (lane&15), site = q*4 + reg.
__global__ __launch_bounds__(256) void feats_kernel(
        const int* __restrict__ loc, const uint2* __restrict__ pfm,
        const float* __restrict__ wgt, const float* __restrict__ gamma,
        const float* __restrict__ beta, const float* __restrict__ mean,
        const float* __restrict__ var, const int* __restrict__ owner,
        unsigned short* __restrict__ feats) {
    __shared__ uint4 WB[4 * KK * 64];   // [t][i][lane] -> 8 f16; 28672 B
    for (int e = threadIdx.x; e < 4 * KK * 64; e += 256) {
        const int t = e / (KK * 64);
        const int rem = e - t * KK * 64;
        const int i = rem >> 6, l = rem & 63;
        const int cout = t * 16 + (l & 15);
        const int q = l >> 4;
        H8U w;
        #pragma unroll
        for (int j = 0; j < 8; ++j) {
            const int kl = q * 8 + j, px = kl >> 2, ci = kl & 3;
            const float v = (px < KK && ci < 3)
                              ? wgt[((i * KK + px) * 3 + ci) * COUT + cout] : 0.0f;
            w.e[j] = (_Float16)v;
        }
        WB[e] = w.u;
    }
    const bool is64 = detect_is64(loc);
    __syncthreads();

    const int lane = threadIdx.x & 63;
    const int q = lane >> 4;
    const int n0 = (blockIdx.x * 4 + (threadIdx.x >> 6)) * 16;

    // A-side site (m = lane&15)
    const int nA = min(n0 + (lane & 15), NS - 1);
    int rA, cA;
    if (is64) { rA = loc[4 * nA]; cA = loc[4 * nA + 2]; }
    else      { rA = loc[2 * nA]; cA = loc[2 * nA + 1]; }
    int aidx = rA * PWX + cA + 2 * q;   // uint2 index; +PWX per row step

    // store-side sites (m = q*4 + p) -> alive mask
    bool alive[4];
    #pragma unroll
    for (int p = 0; p < 4; ++p) {
        const int nS = n0 + q * 4 + p;
        const int nSc = min(nS, NS - 1);
        int r, c;
        if (is64) { r = loc[4 * nSc]; c = loc[4 * nSc + 2]; }
        else      { r = loc[2 * nSc]; c = loc[2 * nSc + 1]; }
        alive[p] = (nS < NS) && (owner[r * WW + c] == nS);
    }

    // BN params for cout = t*16 + (lane&15)
    float invt[4], bist[4];
    #pragma unroll
    for (int t = 0; t < 4; ++t) {
        const int co = t * 16 + (lane & 15);
        const float iv = gamma[co] * rsqrtf(var[co] + 1e-5f);
        invt[t] = iv; bist[t] = beta[co] - mean[co] * iv;
    }

    f4 acc[4] = {f4{0,0,0,0}, f4{0,0,0,0}, f4{0,0,0,0}, f4{0,0,0,0}};
    #pragma unroll
    for (int i = 0; i < KK; ++i) {
        H8U a;
        a.u = *(const u4a*)(pfm + aidx + i * PWX);   // 16B gather, vmcnt
        #pragma unroll
        for (int t = 0; t < 4; ++t) {
            H8U b;
            b.u = WB[(t * KK + i) * 64 + lane];       // ds_read_b128
            acc[t] = __builtin_amdgcn_mfma_f32_16x16x32_f16(a.h, b.h, acc[t], 0, 0, 0);
        }
    }

    unsigned short* dump = feats + (size_t)NS * COUT;  // scratch slot
    #pragma unroll
    for (int t = 0; t < 4; ++t) {
        #pragma unroll
        for (int p = 0; p < 4; ++p) {
            const float v = fmaxf(acc[t][p] * invt[t] + bist[t], 0.0f);
            const int nS = n0 + q * 4 + p;
            unsigned short* addr = alive[p]
                ? feats + (size_t)nS * COUT + t * 16 + (lane & 15)
                : dump + lane;
            *addr = f2bf(v);
        }
    }
}

// ---- 3x3 stride-2 max pool; 4 px/wave; 27 unconditional clamped gathers ----
// (R6 structure: batched independent loads, single drain -> MLP hides L2 lat.)
__global__ __launch_bounds__(256) void pool_kernel(
        const int* __restrict__ owner, const unsigned short* __restrict__ feats,
        float* __restrict__ out) {
    const int lane = threadIdx.x & 63;
    const int TPR = 80;  // ceil(319/4)
    const int task = __builtin_amdgcn_readfirstlane(blockIdx.x * 4 + (threadIdx.x >> 6));
    if (task >= OHh * TPR) return;
    const int oh = task / TPR, ow0 = (task % TPR) * 4;
    const int r0 = oh * 2, c0 = ow0 * 2;

    int ov[3][9];
    #pragma unroll
    for (int dy = 0; dy < 3; ++dy)
        __builtin_memcpy(&ov[dy][0], owner + (r0 + dy) * WW + c0, 36);  // uniform

    float v[3][9];
    #pragma unroll
    for (int dy = 0; dy < 3; ++dy)
        #pragma unroll
        for (int dx = 0; dx < 9; ++dx) {
            const int o = ov[dy][dx];
            const int oc = o < 0 ? 0 : o;
            const float f = bf2f(feats[(size_t)oc * COUT + lane]);
            v[dy][dx] = (o >= 0) ? f : 0.0f;
        }

    #pragma unroll
    for (int qq = 0; qq < 4; ++qq) {
        const int ow = ow0 + qq;
        if (ow >= OWw) break;
        float m = 0.0f;
        #pragma unroll
        for (int dy = 0; dy < 3; ++dy)
            #pragma unroll
            for (int dx = 0; dx < 3; ++dx)
                m = fmaxf(m, v[dy][2 * qq + dx]);
        out[(size_t)(oh * OWw + ow) * COUT + lane] = m;
    }
}

extern "C" void kernel_launch(void* const* d_in, const int* in_sizes, int n_in,
                              void* d_out, int out_size, void* d_ws, size_t ws_size,
                              hipStream_t stream) {
    const int*   loc   = (const int*)d_in[0];
    const float* fm    = (const float*)d_in[1];
    const float* wgt   = (const float*)d_in[2];
    const float* gamma = (const float*)d_in[3];
    const float* beta  = (const float*)d_in[4];
    const float* mean  = (const float*)d_in[5];
    const float* var   = (const float*)d_in[6];
    float* out = (float*)d_out;

    char* ws = (char*)d_ws;
    int* owner = (int*)ws;                                        // 1638400 B
    unsigned short* feats = (unsigned short*)(ws + 1638400);      // 12.8 MB + dump
    uint2* pfm = (uint2*)(ws + 1638400 + (size_t)NS * COUT * 2 + 256);
    // pfm: 646*648*8 = 3.35 MB; total ~17.8 MB

    hipMemsetAsync(owner, 0xFF, (size_t)HH * WW * sizeof(int), stream);  // owner=-1
    prep_kernel<<<OWNER_BLKS + PAD_BLKS, 256, 0, stream>>>(loc, fm, owner, pfm);
    feats_kernel<<<NBLK, 256, 0, stream>>>(loc, pfm, wgt, gamma, beta, mean, var,
                                           owner, feats);
    pool_kernel<<<(OHh * 80 + 3) / 4, 256, 0, stream>>>(owner, feats, out);
}

// Round 9
// 112.888 us; speedup vs baseline: 2.0047x; 1.0772x over previous
//
#include <hip/hip_runtime.h>

#define HH 640
#define WW 640
#define COUT 64
#define KK 7
#define NS 100000
#define OHh 319
#define OWw 319
#define PWY 646                 // pfm rows
#define PWX 648                 // pfm row stride in pixels (8 B each)
#define OWNER_BLKS 391          // ceil(NS/256)
#define PAD_BLKS ((PWY * PWX / 2 + 255) / 256)   // 2 px per thread = 818
#define NBLK 1563               // ceil(NS/64): 64 sites per block (4 waves x 16)
#define NWB (4 * KK * 64)       // 1792 uint4 entries of staged weights

typedef _Float16 half2_t __attribute__((ext_vector_type(2)));
typedef _Float16 h8 __attribute__((ext_vector_type(8)));
typedef float f4 __attribute__((ext_vector_type(4)));
typedef uint4 u4a __attribute__((aligned(8)));   // 16B load at 8B alignment

union H2U { unsigned u; half2_t h; };
union H8U { uint4 u; h8 h; _Float16 e[8]; };

// bf16 helpers (RNE)
__device__ __forceinline__ unsigned short f2bf(float x) {
    unsigned u = __float_as_uint(x);
    return (unsigned short)((u + 0x7FFFu + ((u >> 16) & 1u)) >> 16);
}
__device__ __forceinline__ float bf2f(unsigned short b) {
    return __uint_as_float((unsigned)b << 16);
}

// Per-wave int64/int32 layout detection: OR of the first 64 odd dwords.
__device__ __forceinline__ bool detect_is64(const int* __restrict__ loc) {
    const int smp = loc[1 + 2 * (int)(threadIdx.x & 63)];
    return __ballot(smp != 0) == 0ULL;
}

// ---- fused prep: owner scatter | fp16 pad/pack | weight swizzle + BN ----
// pfm: per pixel uint2 = {pack(c0,c1), pack(c2,0)}; pfm[r][c] == fm[r-3][c-3].
// wbg[e=(t*7+i)*64+lane]: 8 f16 = B-frag(k=q*8..q*8+7, cout=t*16+(lane&15)).
// bn[0..63]=gamma*rsqrt(var+eps), bn[64..127]=beta-mean*inv.
__global__ __launch_bounds__(256) void prep_kernel(
        const int* __restrict__ loc, const float* __restrict__ fm,
        const float* __restrict__ wgt, const float* __restrict__ gamma,
        const float* __restrict__ beta, const float* __restrict__ mean,
        const float* __restrict__ var,
        int* __restrict__ owner, uint2* __restrict__ pfm,
        uint4* __restrict__ wbg, float* __restrict__ bn) {
    if (blockIdx.x < OWNER_BLKS) {
        const bool is64 = detect_is64(loc);
        const int n = blockIdx.x * 256 + threadIdx.x;
        if (n < NS) {
            int r, c;
            if (is64) { r = loc[4 * n]; c = loc[4 * n + 2]; }
            else      { r = loc[2 * n]; c = loc[2 * n + 1]; }
            atomicMax(&owner[r * WW + c], n);
        }
    } else if (blockIdx.x < OWNER_BLKS + PAD_BLKS) {
        const int pair = (blockIdx.x - OWNER_BLKS) * 256 + threadIdx.x;
        const int pix = pair * 2;
        if (pix < PWY * PWX) {
            const int r = pix / PWX, c = pix - r * PWX;
            uint4 o;
            H2U a0, b0, a1, b1;
            a0.u = b0.u = a1.u = b1.u = 0;
            if (r >= 3 && r < 643) {
                const float* s = fm + ((size_t)(r - 3) * WW + (c - 3)) * 3;
                if (c >= 3 && c < 643) {
                    a0.h = half2_t{(_Float16)s[0], (_Float16)s[1]};
                    b0.h = half2_t{(_Float16)s[2], (_Float16)0};
                }
                if (c + 1 >= 3 && c + 1 < 643) {
                    a1.h = half2_t{(_Float16)s[3], (_Float16)s[4]};
                    b1.h = half2_t{(_Float16)s[5], (_Float16)0};
                }
            }
            o.x = a0.u; o.y = b0.u; o.z = a1.u; o.w = b1.u;
            *(uint4*)(pfm + pix) = o;   // 16B aligned (pix even)
        }
    } else {
        // single weight-staging block (runs once, not once per feats block)
        for (int e = threadIdx.x; e < NWB; e += 256) {
            const int t = e / (KK * 64);
            const int rem = e - t * KK * 64;
            const int i = rem >> 6, l = rem & 63;
            const int cout = t * 16 + (l & 15);
            const int q = l >> 4;
            H8U w;
            #pragma unroll
            for (int j = 0; j < 8; ++j) {
                const int kl = q * 8 + j, px = kl >> 2, ci = kl & 3;
                const float v = (px < KK && ci < 3)
                                  ? wgt[((i * KK + px) * 3 + ci) * COUT + cout] : 0.0f;
                w.e[j] = (_Float16)v;
            }
            wbg[e] = w.u;
        }
        if (threadIdx.x < COUT) {
            const int co = threadIdx.x;
            const float iv = gamma[co] * rsqrtf(var[co] + 1e-5f);
            bn[co] = iv;
            bn[COUT + co] = beta[co] - mean[co] * iv;
        }
    }
}

// ---- MFMA feats: 16 sites/wave, D[site][cout] = patch . W, +BN+ReLU ----
// K = 224 (7 rows x 8 px x 4 ch; px7 & ch3 zero-weighted).
// A-frag: lane(m=lane&15, q=lane>>4) holds patch[m][k=q*8..q*8+7] = 2 pixels,
//         one 16B global load per row step.  B-frag: LDS ds_read_b128.
// C/D: cout = t*16 + (lane&15), site = q*4 + reg.
// No owner check: losing duplicates' feats rows are simply never read by pool.
__global__ __launch_bounds__(256) void feats_kernel(
        const int* __restrict__ loc, const uint2* __restrict__ pfm,
        const uint4* __restrict__ wbg, const float* __restrict__ bn,
        unsigned short* __restrict__ feats) {
    __shared__ uint4 WB[NWB];   // 28672 B
    #pragma unroll
    for (int e = 0; e < NWB / 256; ++e)
        WB[e * 256 + threadIdx.x] = wbg[e * 256 + threadIdx.x];  // coalesced
    const bool is64 = detect_is64(loc);
    __syncthreads();

    const int lane = threadIdx.x & 63;
    const int m = lane & 15;
    const int q = lane >> 4;
    const int n0 = (blockIdx.x * 4 + (threadIdx.x >> 6)) * 16;
    if (n0 >= NS) return;

    // A-side site
    const int nA = n0 + m;   // 100000 % 16 == 0, always in range
    int rA, cA;
    if (is64) { rA = loc[4 * nA]; cA = loc[4 * nA + 2]; }
    else      { rA = loc[2 * nA]; cA = loc[2 * nA + 1]; }
    const int aidx = rA * PWX + cA + 2 * q;   // uint2 index; +PWX per row

    // BN params for cout = t*16 + m (precomputed in prep)
    float invt[4], bist[4];
    #pragma unroll
    for (int t = 0; t < 4; ++t) {
        invt[t] = bn[t * 16 + m];
        bist[t] = bn[COUT + t * 16 + m];
    }

    f4 acc[4] = {f4{0,0,0,0}, f4{0,0,0,0}, f4{0,0,0,0}, f4{0,0,0,0}};
    #pragma unroll
    for (int i = 0; i < KK; ++i) {
        H8U a;
        a.u = *(const u4a*)(pfm + aidx + i * PWX);   // 16B gather, vmcnt
        #pragma unroll
        for (int t = 0; t < 4; ++t) {
            H8U b;
            b.u = WB[(t * KK + i) * 64 + lane];       // ds_read_b128
            acc[t] = __builtin_amdgcn_mfma_f32_16x16x32_f16(a.h, b.h, acc[t], 0, 0, 0);
        }
    }

    #pragma unroll
    for (int t = 0; t < 4; ++t) {
        #pragma unroll
        for (int p = 0; p < 4; ++p) {
            const float v = fmaxf(acc[t][p] * invt[t] + bist[t], 0.0f);
            const int nS = n0 + q * 4 + p;
            feats[(size_t)nS * COUT + t * 16 + m] = f2bf(v);
        }
    }
}

// ---- 3x3 stride-2 max pool; 4 px/wave; 27 unconditional clamped gathers ----
__global__ __launch_bounds__(256) void pool_kernel(
        const int* __restrict__ owner, const unsigned short* __restrict__ feats,
        float* __restrict__ out) {
    const int lane = threadIdx.x & 63;
    const int TPR = 80;  // ceil(319/4)
    const int task = __builtin_amdgcn_readfirstlane(blockIdx.x * 4 + (threadIdx.x >> 6));
    if (task >= OHh * TPR) return;
    const int oh = task / TPR, ow0 = (task % TPR) * 4;
    const int r0 = oh * 2, c0 = ow0 * 2;

    int ov[3][9];
    #pragma unroll
    for (int dy = 0; dy < 3; ++dy)
        __builtin_memcpy(&ov[dy][0], owner + (r0 + dy) * WW + c0, 36);  // uniform

    float v[3][9];
    #pragma unroll
    for (int dy = 0; dy < 3; ++dy)
        #pragma unroll
        for (int dx = 0; dx < 9; ++dx) {
            const int o = ov[dy][dx];
            const int oc = o < 0 ? 0 : o;
            const float f = bf2f(feats[(size_t)oc * COUT + lane]);
            v[dy][dx] = (o >= 0) ? f : 0.0f;
        }

    #pragma unroll
    for (int qq = 0; qq < 4; ++qq) {
        const int ow = ow0 + qq;
        if (ow >= OWw) break;
        float m = 0.0f;
        #pragma unroll
        for (int dy = 0; dy < 3; ++dy)
            #pragma unroll
            for (int dx = 0; dx < 3; ++dx)
                m = fmaxf(m, v[dy][2 * qq + dx]);
        out[(size_t)(oh * OWw + ow) * COUT + lane] = m;
    }
}

extern "C" void kernel_launch(void* const* d_in, const int* in_sizes, int n_in,
                              void* d_out, int out_size, void* d_ws, size_t ws_size,
                              hipStream_t stream) {
    const int*   loc   = (const int*)d_in[0];
    const float* fm    = (const float*)d_in[1];
    const float* wgt   = (const float*)d_in[2];
    const float* gamma = (const float*)d_in[3];
    const float* beta  = (const float*)d_in[4];
    const float* mean  = (const float*)d_in[5];
    const float* var   = (const float*)d_in[6];
    float* out = (float*)d_out;

    char* ws = (char*)d_ws;
    int* owner = (int*)ws;                                        // 1638400 B
    unsigned short* feats = (unsigned short*)(ws + 1638400);      // 12.8 MB
    uint2* pfm = (uint2*)(ws + 1638400 + (size_t)NS * COUT * 2);  // 3.35 MB
    char* ws2 = ws + 1638400 + (size_t)NS * COUT * 2 + (size_t)PWY * PWX * 8;
    uint4* wbg = (uint4*)ws2;                                     // 28672 B
    float* bn  = (float*)(ws2 + NWB * 16);                        // 512 B
    // total ~17.9 MB

    hipMemsetAsync(owner, 0xFF, (size_t)HH * WW * sizeof(int), stream);  // owner=-1
    prep_kernel<<<OWNER_BLKS + PAD_BLKS + 1, 256, 0, stream>>>(
        loc, fm, wgt, gamma, beta, mean, var, owner, pfm, wbg, bn);
    feats_kernel<<<NBLK, 256, 0, stream>>>(loc, pfm, wbg, bn, feats);
    pool_kernel<<<(OHh * 80 + 3) / 4, 256, 0, stream>>>(owner, feats, out);
}